// Round 10
// baseline (51.380 us; speedup 1.0000x reference)
//
#include <hip/hip_runtime.h>
#include <hip/hip_bf16.h>
#include <math.h>

#define B_ 128
#define IN_ 1024
#define D_ 128
#define H_ 512
#define S_ 256

typedef __attribute__((ext_vector_type(8))) short short8v;
typedef __attribute__((ext_vector_type(8))) unsigned short ushort8v;
typedef __attribute__((ext_vector_type(4))) unsigned short ushort4v;
typedef __attribute__((ext_vector_type(4))) float f32x4;

__device__ __forceinline__ float softplusf(float x) {
  return fmaxf(x, 0.f) + log1pf(expf(-fabsf(x)));
}

__device__ __forceinline__ unsigned short f2bf(float f) {
  unsigned u = __float_as_uint(f);
  unsigned r = (u + 0x7fff + ((u >> 16) & 1)) >> 16;   // RNE
  return (unsigned short)r;
}

// ============ Bp pack (round-5 verified, standalone): 64 blocks x 256 ============
// Bp[frag*512 + l*8 + j] = bf16(W1w[h][k]); frag=hblk*4+ks, h=hblk*16+(l&15),
// k=ks*32+(l>>4)*8+j
__global__ __launch_bounds__(256) void Bpack(const float* __restrict__ W1,
                                             unsigned short* __restrict__ Bp) {
  const int o = (blockIdx.x * 256 + threadIdx.x) * 4;
  const int frag = o >> 9;
  const int l = (o >> 3) & 63;
  const int j0 = o & 7;
  const int h = (frag >> 2) * 16 + (l & 15);
  const int k0 = (frag & 3) * 32 + ((l >> 4) << 3) + j0;
  const float4 v = *(const float4*)(W1 + (size_t)h * 256 + 128 + k0);
  ushort4v u;
  u[0] = f2bf(v.x); u[1] = f2bf(v.y); u[2] = f2bf(v.z); u[3] = f2bf(v.w);
  *(ushort4v*)(Bp + o) = u;
}

// ============ mega kernel: one block per b, 1024 threads ============
// phases: load vectors -> stage A-tile -> in-block prep (pwx/pxw/zw)
//         -> MFMA GEMM -> fused logsumexp + combine -> out[b]
__global__ __launch_bounds__(1024) void Kmega(
    const float* __restrict__ x, const float* __restrict__ w,
    const float* __restrict__ z, const float* __restrict__ wt,
    const float* __restrict__ W, const float* __restrict__ bvec,
    const float* __restrict__ cvec, const float* __restrict__ W1,
    const float* __restrict__ b1, const float* __restrict__ W2,
    const float* __restrict__ b2, const unsigned short* __restrict__ Bp,
    float* __restrict__ out) {
  const int b = blockIdx.x;
  const int t = threadIdx.x;
  const int lane = t & 63, wvid = t >> 6;        // 16 waves

  __shared__ unsigned short atile[256 * 128];    // 64 KB, XOR-swizzled bf16
  __shared__ float zb1s[H_];
  __shared__ float w2s[H_];
  __shared__ float xs[IN_];
  __shared__ float wsv[128], zsv[128];
  __shared__ float p2[1024];                     // pwx partials [8][128]
  __shared__ float red[16][64];
  __shared__ float sred3[16][3];
  __shared__ float mred[4], ered[4];

  // ---- phase 0: small vectors ----
  xs[t] = x[(size_t)b * IN_ + t];
  if (t < 128) { wsv[t] = w[b * 128 + t]; zsv[t] = z[b * 128 + t]; }
  if (t < 512) w2s[t] = W2[t];
  __syncthreads();

  // ---- stage A: 256 rows x 128 d, fp32 -> bf16, granule swizzle g ^= r&15 ----
  {
    const int r = t >> 2;                        // 0..255
    const int g0 = (t & 3) * 4;
    const float* __restrict__ src = wt + ((size_t)r * B_ + b) * D_;
    #pragma unroll
    for (int gg = 0; gg < 4; ++gg) {
      const int g = g0 + gg;
      const float4 v0 = *(const float4*)(src + g * 8);
      const float4 v1 = *(const float4*)(src + g * 8 + 4);
      ushort8v u;
      u[0] = f2bf(v0.x); u[1] = f2bf(v0.y); u[2] = f2bf(v0.z); u[3] = f2bf(v0.w);
      u[4] = f2bf(v1.x); u[5] = f2bf(v1.y); u[6] = f2bf(v1.z); u[7] = f2bf(v1.w);
      *(ushort8v*)&atile[r * 128 + ((g ^ (r & 15)) << 3)] = u;
    }
  }

  // ---- prep 1: pwx partial logits (thread = (d, ks of 8), 128 i each) ----
  {
    const int d = t & 127, ks = t >> 7;
    const float* __restrict__ Wp = W + (size_t)(ks * 128) * D_ + d;
    float s = 0.f;
    #pragma unroll 8
    for (int i = 0; i < 128; ++i) s = fmaf(xs[ks * 128 + i], Wp[(size_t)i * D_], s);
    p2[ks * 128 + d] = s;
  }
  __syncthreads();

  float pwx_term = 0.f, pxw_term = 0.f, fzw_term = 0.f;

  // ---- prep 2: pwx finish (t < 128) ----
  if (t < 128) {
    float lg = bvec[t];
    #pragma unroll
    for (int k2 = 0; k2 < 8; ++k2) lg += p2[k2 * 128 + t];
    pwx_term = wsv[t] * lg - softplusf(lg);
  }

  // ---- prep 3: pxw (64 rows in flight, 16 lanes/row — round-5 pattern) ----
  {
    const int chunk = t & 15, rg = t >> 4;       // rg 0..63
    float wreg[8];
    #pragma unroll
    for (int j = 0; j < 8; ++j) wreg[j] = wsv[chunk * 8 + j];
    #pragma unroll 2
    for (int it = 0; it < 16; ++it) {
      const int i = it * 64 + rg;
      const float4* __restrict__ rp = (const float4*)(W + (size_t)i * D_ + chunk * 8);
      const float4 va = rp[0], vb = rp[1];
      float dot = 0.f;
      dot = fmaf(va.x, wreg[0], dot); dot = fmaf(va.y, wreg[1], dot);
      dot = fmaf(va.z, wreg[2], dot); dot = fmaf(va.w, wreg[3], dot);
      dot = fmaf(vb.x, wreg[4], dot); dot = fmaf(vb.y, wreg[5], dot);
      dot = fmaf(vb.z, wreg[6], dot); dot = fmaf(vb.w, wreg[7], dot);
      dot += __shfl_xor(dot, 1); dot += __shfl_xor(dot, 2);
      dot += __shfl_xor(dot, 4); dot += __shfl_xor(dot, 8);
      if (chunk == 0) {
        const float lg = dot + cvec[i];
        pxw_term += xs[i] * lg - softplusf(lg);
      }
    }
  }

  // ---- prep 4: zw (64 rows in flight, 16 lanes/row — round-5 pattern) ----
  {
    const int c16 = t & 15, rg = t >> 4;
    float zreg[16];
    #pragma unroll
    for (int j = 0; j < 16; ++j)
      zreg[j] = (c16 < 8) ? zsv[c16 * 16 + j] : wsv[(c16 - 8) * 16 + j];
    #pragma unroll 2
    for (int it = 0; it < 8; ++it) {
      const int h = it * 64 + rg;
      const float4* __restrict__ rp = (const float4*)(W1 + (size_t)h * 256 + c16 * 16);
      float dot = 0.f;
      #pragma unroll
      for (int q = 0; q < 4; ++q) {
        const float4 v = rp[q];
        dot = fmaf(v.x, zreg[4 * q + 0], dot);
        dot = fmaf(v.y, zreg[4 * q + 1], dot);
        dot = fmaf(v.z, zreg[4 * q + 2], dot);
        dot = fmaf(v.w, zreg[4 * q + 3], dot);
      }
      dot += __shfl_xor(dot, 1); dot += __shfl_xor(dot, 2);
      dot += __shfl_xor(dot, 4);
      const float other = __shfl_xor(dot, 8);    // pair z-sum with w-sum
      if (c16 == 0) {
        const float zp = dot + b1[h];
        zb1s[h] = zp;                            // stays in LDS
        fzw_term += fmaxf(zp + other, 0.f) * w2s[h];
      }
    }
  }

  // ---- per-wave reduce the 3 prep scalars ----
  #pragma unroll
  for (int o = 1; o < 64; o <<= 1) {
    pwx_term += __shfl_xor(pwx_term, o);
    pxw_term += __shfl_xor(pxw_term, o);
    fzw_term += __shfl_xor(fzw_term, o);
  }
  if (lane == 0) {
    sred3[wvid][0] = pwx_term;
    sred3[wvid][1] = pxw_term;
    sred3[wvid][2] = fzw_term;
  }
  __syncthreads();   // atile, zb1s, sred3 all ready

  // ===== GEMM (round-5 verified body) =====
  const int sc = wvid >> 2, nh = (wvid >> 1) & 1, nth = wvid & 1;
  short8v afr[4][4];
  #pragma unroll
  for (int m = 0; m < 4; ++m) {
    const int arow = sc * 64 + m * 16 + (lane & 15);
    #pragma unroll
    for (int ks = 0; ks < 4; ++ks) {
      const int g = ks * 4 + (lane >> 4);
      afr[m][ks] = *(const short8v*)&atile[arow * 128 + ((g ^ (arow & 15)) << 3)];
    }
  }

  float fsum[4][4];
  #pragma unroll
  for (int m = 0; m < 4; ++m)
    #pragma unroll
    for (int j = 0; j < 4; ++j) fsum[m][j] = 0.f;

  const int hl = lane & 15;
  #pragma unroll 2
  for (int nt = 0; nt < 8; ++nt) {
    const int hblk = nh * 16 + nth * 8 + nt;
    const int hrow = hblk * 16 + hl;
    f32x4 acc0 = {0.f,0.f,0.f,0.f}, acc1 = {0.f,0.f,0.f,0.f};
    f32x4 acc2 = {0.f,0.f,0.f,0.f}, acc3 = {0.f,0.f,0.f,0.f};
    #pragma unroll
    for (int ks = 0; ks < 4; ++ks) {
      const int frag = hblk * 4 + ks;
      const short8v bfr = *(const short8v*)(Bp + ((size_t)frag << 9) + (lane << 3));
      acc0 = __builtin_amdgcn_mfma_f32_16x16x32_bf16(afr[0][ks], bfr, acc0, 0, 0, 0);
      acc1 = __builtin_amdgcn_mfma_f32_16x16x32_bf16(afr[1][ks], bfr, acc1, 0, 0, 0);
      acc2 = __builtin_amdgcn_mfma_f32_16x16x32_bf16(afr[2][ks], bfr, acc2, 0, 0, 0);
      acc3 = __builtin_amdgcn_mfma_f32_16x16x32_bf16(afr[3][ks], bfr, acc3, 0, 0, 0);
    }
    const float zv = zb1s[hrow], wgt = w2s[hrow];
    #pragma unroll
    for (int j = 0; j < 4; ++j) {
      fsum[0][j] += fmaxf(acc0[j] + zv, 0.f) * wgt;
      fsum[1][j] += fmaxf(acc1[j] + zv, 0.f) * wgt;
      fsum[2][j] += fmaxf(acc2[j] + zv, 0.f) * wgt;
      fsum[3][j] += fmaxf(acc3[j] + zv, 0.f) * wgt;
    }
  }
  #pragma unroll
  for (int m = 0; m < 4; ++m)
    #pragma unroll
    for (int j = 0; j < 4; ++j) {
      float v = fsum[m][j];
      v += __shfl_xor(v, 1); v += __shfl_xor(v, 2);
      v += __shfl_xor(v, 4); v += __shfl_xor(v, 8);
      fsum[m][j] = v;
    }
  if (hl == 0) {
    const int rb = (lane >> 4) * 4;
    #pragma unroll
    for (int m = 0; m < 4; ++m)
      #pragma unroll
      for (int j = 0; j < 4; ++j)
        red[wvid][m * 16 + rb + j] = fsum[m][j];
  }
  __syncthreads();

  // ===== fused finisher =====
  float fval = 0.f;
  if (t < 256) {
    const int sc2 = t >> 6, r = t & 63;
    fval = red[sc2 * 4 + 0][r] + red[sc2 * 4 + 1][r]
         + red[sc2 * 4 + 2][r] + red[sc2 * 4 + 3][r] + b2[0];
    float mm = fval;
    #pragma unroll
    for (int o = 1; o < 64; o <<= 1) mm = fmaxf(mm, __shfl_xor(mm, o));
    if (lane == 0) mred[wvid] = mm;
  }
  __syncthreads();
  if (t < 256) {
    const float mm = fmaxf(fmaxf(mred[0], mred[1]), fmaxf(mred[2], mred[3]));
    float e = expf(fval - mm);
    #pragma unroll
    for (int o = 1; o < 64; o <<= 1) e += __shfl_xor(e, o);
    if (lane == 0) ered[wvid] = e;
  }
  __syncthreads();
  if (t == 0) {
    const float mm = fmaxf(fmaxf(mred[0], mred[1]), fmaxf(mred[2], mred[3]));
    const float tot = ered[0] + ered[1] + ered[2] + ered[3];
    const float logZ = mm + logf(tot) - logf((float)S_) + (float)D_ * logf(2.f);
    float pwx = 0.f, pxw = 0.f, fzw = 0.f;
    #pragma unroll
    for (int w16 = 0; w16 < 16; ++w16) {
      pwx += sred3[w16][0];
      pxw += sred3[w16][1];
      fzw += sred3[w16][2];
    }
    fzw += b2[0];
    const float r_wz = fminf(fzw - logZ, 0.f);
    out[b] = -(pxw - pwx + r_wz);
  }
}

extern "C" void kernel_launch(void* const* d_in, const int* in_sizes, int n_in,
                              void* d_out, int out_size, void* d_ws, size_t ws_size,
                              hipStream_t stream) {
  const float* x    = (const float*)d_in[0];
  // d_in[1] = y, unused
  const float* w    = (const float*)d_in[2];
  const float* z    = (const float*)d_in[3];
  const float* wt   = (const float*)d_in[4];
  const float* W    = (const float*)d_in[5];
  const float* bvec = (const float*)d_in[6];
  const float* cvec = (const float*)d_in[7];
  const float* W1   = (const float*)d_in[8];
  const float* b1   = (const float*)d_in[9];
  const float* W2   = (const float*)d_in[10];
  const float* b2   = (const float*)d_in[11];

  unsigned short* Bp = (unsigned short*)d_ws;   // 65536 ushorts = 128 KB
  float* out = (float*)d_out;

  hipLaunchKernelGGL(Bpack, dim3(64), dim3(256), 0, stream, W1, Bp);
  hipLaunchKernelGGL(Kmega, dim3(B_), dim3(1024), 0, stream,
                     x, w, z, wt, W, bvec, cvec, W1, b1, W2, b2, Bp, out);
}